// Round 2
// baseline (8826.881 us; speedup 1.0000x reference)
//
#include <hip/hip_runtime.h>
#include <hip/hip_bf16.h>

#define DI __device__ __forceinline__

// ---------------- workspace layout (in floats) ----------------
// Region B: x0 (4.19M floats) then reused for x2 (16.78M)
// Region A: x1 (8.39M) then reused for x3 (33.55M)
static constexpr size_t OFF_REGB = 0;
static constexpr size_t OFF_REGA = 16777216;           // 64 MB in
static constexpr size_t OFF_SC   = 50331648;           // 192 MB in
static constexpr size_t OFF_SH   = OFF_SC + 262144;

// ---------------- fc1: x0[b,d,hw] = relu(sum_c feat[b,c,hw] * W[c,d] + b[d]) ----------------
__global__ __launch_bounds__(256)
void fc_kernel(const float* __restrict__ feat, const float* __restrict__ fw,
               const float* __restrict__ fb, float* __restrict__ x0)
{
  constexpr int CI = 256, CO = 512, S2 = 16;
  __shared__ __align__(16) float xs[CI * S2];
  const int b = blockIdx.x, t = threadIdx.x;
  const float4* fg = (const float4*)(feat + (size_t)b * CI * S2);
#pragma unroll
  for (int j = 0; j < 4; ++j)
    ((float4*)xs)[t + j * 256] = fg[t + j * 256];
  __syncthreads();
  const int hw = t & 15;
  const int d0 = (t >> 4) * 32;
  float acc[32];
#pragma unroll
  for (int j = 0; j < 32; ++j) acc[j] = 0.f;
  for (int c = 0; c < CI; ++c) {
    float xv = xs[c * S2 + hw];
    const float4* wr = (const float4*)(fw + c * CO + d0);
#pragma unroll
    for (int q = 0; q < 8; ++q) {
      float4 w4 = wr[q];
      acc[q * 4 + 0] += xv * w4.x;
      acc[q * 4 + 1] += xv * w4.y;
      acc[q * 4 + 2] += xv * w4.z;
      acc[q * 4 + 3] += xv * w4.w;
    }
  }
#pragma unroll
  for (int j = 0; j < 32; ++j) {
    int d = d0 + j;
    x0[((size_t)b * CO + d) * S2 + hw] = fmaxf(acc[j] + fb[d], 0.f);
  }
}

// ---------------- per-(b,c) norm stats -> scale/shift ----------------
__global__ void gn_stats_kernel(const float* __restrict__ x, const float* __restrict__ g,
                                const float* __restrict__ be, float* __restrict__ sc,
                                float* __restrict__ sh, int C, int S2)
{
  int wid = (blockIdx.x * 256 + threadIdx.x) >> 6;
  int lane = threadIdx.x & 63;
  const float* xp = x + (size_t)wid * S2;
  float s = 0.f, s2 = 0.f;
  for (int j = lane; j < S2; j += 64) { float v = xp[j]; s += v; s2 += v * v; }
#pragma unroll
  for (int off = 32; off; off >>= 1) { s += __shfl_xor(s, off, 64); s2 += __shfl_xor(s2, off, 64); }
  if (lane == 0) {
    float inv = 1.f / (float)S2;
    float mu = s * inv;
    float var = fmaxf(s2 * inv - mu * mu, 0.f);
    float rstd = rsqrtf(var + 1e-5f);
    int c = wid % C;
    float gamma = g ? g[c] : 1.f;
    float beta  = be ? be[c] : 0.f;
    float scale = gamma * rstd;
    sc[wid] = scale;
    sh[wid] = beta - mu * scale;
  }
}

// ---------------- deconv stage: y = relu(deconv(gn(x)) + bias) ----------------
// ConvTranspose2d(CI, CO, 3, stride=2, pad=1, output_pad=1) as a gather
// (reference: lhs_dilation=2, pad (1,2), unflipped weights):
// output (oy,ox) taps (ky,kx) with (oy+ky-1) even, iy=(oy+ky-1)/2 in range.
// even coord -> 1 tap (k=1); odd -> 2 taps (k=0,2). Zero-padded uniform 4-tap inner loop.
template<int CI, int HIN, int OBLK, int NT_SP, int CHUNK>
__global__ __launch_bounds__(256)
void deconv_kernel(const float* __restrict__ x, const float* __restrict__ sc,
                   const float* __restrict__ sh, const float* __restrict__ w,
                   const float* __restrict__ bias, float* __restrict__ y, int CO)
{
  constexpr int WIN = HIN, WOUT = 2 * HIN;
  constexpr int S2I = HIN * WIN, S2O = 4 * S2I;
  constexpr int NT_O = 256 / NT_SP;
  constexpr int SPT = S2O / NT_SP;
  constexpr int OPT = OBLK / NT_O;
  constexpr int NCH = CI / CHUNK;
  constexpr int OY_STEP = NT_SP / WOUT;
  static_assert(SPT * NT_SP == S2O, "spt");
  static_assert(OPT * NT_O == OBLK, "opt");
  static_assert(CHUNK * S2I == 8192, "lds");
  __shared__ __align__(16) float xs[CHUNK * S2I];

  const int b = blockIdx.y;
  const int o0 = blockIdx.x * OBLK;
  const int t = threadIdx.x;
  const int tsp = t % NT_SP;
  const int to = t / NT_SP;

  const int ox = tsp % WOUT;
  const int oy0 = tsp / WOUT;
  const int px = ox & 1;
  const int tx = ox >> 1;
  const bool xok = (tx + 1) < WIN;
  const int ixA = tx, ixB = xok ? tx + 1 : WIN - 1;
  const int kxA = px ? 0 : 1;
  const int py = oy0 & 1;              // same parity for all k (OY_STEP even or SPT==1)
  const int kyA3 = py ? 0 : 3;
  const bool pxy = px && py;

  int rA[SPT], rB[SPT]; bool yok[SPT];
#pragma unroll
  for (int k = 0; k < SPT; ++k) {
    int oy = oy0 + k * OY_STEP;
    int iy = oy >> 1;
    yok[k] = (iy + 1) < HIN;
    rA[k] = iy * WIN;
    rB[k] = (yok[k] ? iy + 1 : iy) * WIN;
  }

  float acc[OPT][SPT];
#pragma unroll
  for (int m = 0; m < OPT; ++m)
#pragma unroll
    for (int k = 0; k < SPT; ++k) acc[m][k] = 0.f;

  for (int ch = 0; ch < NCH; ++ch) {
    const int c0 = ch * CHUNK;
    if (ch) __syncthreads();
    const float4* xg = (const float4*)(x + ((size_t)b * CI + c0) * S2I);
#pragma unroll
    for (int j = 0; j < (CHUNK * S2I / 1024); ++j) {
      int i4 = t + j * 256;
      int i_loc = (i4 * 4) / S2I;
      float scv = sc[b * CI + c0 + i_loc];
      float shv = sh[b * CI + c0 + i_loc];
      float4 v = xg[i4];
      v.x = v.x * scv + shv;
      v.y = v.y * scv + shv;
      v.z = v.z * scv + shv;
      v.w = v.w * scv + shv;
      ((float4*)xs)[i4] = v;
    }
    __syncthreads();

    for (int i = 0; i < CHUNK; ++i) {
      const float* xr = xs + i * S2I;
      float x00[SPT], x01[SPT], x10[SPT], x11[SPT];
#pragma unroll
      for (int k = 0; k < SPT; ++k) {
        x00[k] = xr[rA[k] + ixA];
        x01[k] = xok ? xr[rA[k] + ixB] : 0.f;
        x10[k] = yok[k] ? xr[rB[k] + ixA] : 0.f;
        x11[k] = (xok && yok[k]) ? xr[rB[k] + ixB] : 0.f;
      }
#pragma unroll
      for (int m = 0; m < OPT; ++m) {
        const float* wr = w + ((size_t)(o0 + to + m * NT_O) * CI + (c0 + i)) * 9;
        float w00 = wr[kyA3 + kxA];
        float w01 = px  ? wr[kyA3 + 2] : 0.f;
        float w10 = py  ? wr[6 + kxA]  : 0.f;
        float w11 = pxy ? wr[8]        : 0.f;
#pragma unroll
        for (int k = 0; k < SPT; ++k)
          acc[m][k] += x00[k] * w00 + x01[k] * w01 + x10[k] * w10 + x11[k] * w11;
      }
    }
  }

#pragma unroll
  for (int m = 0; m < OPT; ++m) {
    int o = o0 + to + m * NT_O;
    float bv = bias[o];
#pragma unroll
    for (int k = 0; k < SPT; ++k) {
      int oy = oy0 + k * OY_STEP;
      y[((size_t)b * CO + o) * S2O + oy * WOUT + ox] = fmaxf(acc[m][k] + bv, 0.f);
    }
  }
}

// ---------------- block reductions ----------------
DI float breduce_sum(float v, float* buf) {
#pragma unroll
  for (int off = 32; off; off >>= 1) v += __shfl_xor(v, off, 64);
  if ((threadIdx.x & 63) == 0) buf[threadIdx.x >> 6] = v;
  __syncthreads();
  float r = (buf[0] + buf[1]) + (buf[2] + buf[3]);
  __syncthreads();
  return r;
}
DI float breduce_max(float v, float* buf) {
#pragma unroll
  for (int off = 32; off; off >>= 1) v = fmaxf(v, __shfl_xor(v, off, 64));
  if ((threadIdx.x & 63) == 0) buf[threadIdx.x >> 6] = v;
  __syncthreads();
  float r = fmaxf(fmaxf(buf[0], buf[1]), fmaxf(buf[2], buf[3]));
  __syncthreads();
  return r;
}

// ---------------- head: norm -> per-action 1x1 conv -> spatial softmax -> coords ----------------
// b_eff (hcb, hgb contribution) is constant over spatial -> softmax-invariant -> dropped.
__global__ __launch_bounds__(256)
void head_kernel(const float* __restrict__ x3, const float* __restrict__ sc,
                 const float* __restrict__ sh, const int* __restrict__ action,
                 const float* __restrict__ hgw, const float* __restrict__ hcw,
                 float* __restrict__ out)
{
  constexpr int C = 64, S = 5, P = 1024;
  const int b = blockIdx.x, t = threadIdx.x;
  const int a = action[b];
  __shared__ float weff[S * C];
  __shared__ float rbuf[4];
  for (int j = t; j < S * C; j += 256) {
    int s = j >> 6, c = j & 63;
    weff[j] = hcw[(a * S + s) * C + c] * hgw[a * C + c];
  }
  __syncthreads();

  float L[S][4];
#pragma unroll
  for (int s = 0; s < S; ++s)
#pragma unroll
    for (int k = 0; k < 4; ++k) L[s][k] = 0.f;

  const float* xb = x3 + (size_t)b * C * P;
  for (int c = 0; c < C; ++c) {
    float scv = sc[b * C + c], shv = sh[b * C + c];
    float xv[4];
#pragma unroll
    for (int k = 0; k < 4; ++k) xv[k] = xb[c * P + t + k * 256] * scv + shv;
#pragma unroll
    for (int s = 0; s < S; ++s) {
      float wv = weff[s * C + c];
#pragma unroll
      for (int k = 0; k < 4; ++k) L[s][k] += xv[k] * wv;
    }
  }

#pragma unroll
  for (int s = 0; s < S; ++s) {
    float m = fmaxf(fmaxf(L[s][0], L[s][1]), fmaxf(L[s][2], L[s][3]));
    m = breduce_max(m, rbuf);
    float se = 0.f, sx = 0.f, sy = 0.f;
#pragma unroll
    for (int k = 0; k < 4; ++k) {
      int p = t + k * 256;
      float e = __expf(L[s][k] - m);
      se += e;
      sx += e * ((float)(p & 31) * (2.f / 31.f) - 1.f);
      sy += e * ((float)(p >> 5) * (2.f / 31.f) - 1.f);
    }
    se = breduce_sum(se, rbuf);
    sx = breduce_sum(sx, rbuf);
    sy = breduce_sum(sy, rbuf);
    if (t == 0) {
      out[(b * S + s) * 2 + 0] = sx / se;
      out[(b * S + s) * 2 + 1] = sy / se;
    }
  }
}

// ---------------- launcher ----------------
extern "C" void kernel_launch(void* const* d_in, const int* in_sizes, int n_in,
                              void* d_out, int out_size, void* d_ws, size_t ws_size,
                              hipStream_t stream)
{
  (void)in_sizes; (void)n_in; (void)out_size; (void)ws_size;
  const float* feat   = (const float*)d_in[0];
  const int*   action = (const int*)d_in[1];
  // d_in[2] scene_idx unused
  const float* fc_w = (const float*)d_in[3];
  const float* fc_b = (const float*)d_in[4];
  const float* gw0  = (const float*)d_in[5];
  const float* gb0  = (const float*)d_in[6];
  const float* dw0  = (const float*)d_in[7];
  const float* db0  = (const float*)d_in[8];
  const float* gw1  = (const float*)d_in[9];
  const float* gb1  = (const float*)d_in[10];
  const float* dw1  = (const float*)d_in[11];
  const float* db1  = (const float*)d_in[12];
  const float* gw2  = (const float*)d_in[13];
  const float* gb2  = (const float*)d_in[14];
  const float* dw2  = (const float*)d_in[15];
  const float* db2  = (const float*)d_in[16];
  const float* hgw  = (const float*)d_in[17];
  // d_in[18] hgb, d_in[20] hcb: only shift logits uniformly -> softmax-invariant, unused
  const float* hcw  = (const float*)d_in[19];

  float* ws = (float*)d_ws;
  float* x0 = ws + OFF_REGB;
  float* x2 = ws + OFF_REGB;
  float* x1 = ws + OFF_REGA;
  float* x3 = ws + OFF_REGA;
  float* sc = ws + OFF_SC;
  float* sh = ws + OFF_SH;

  fc_kernel<<<512, 256, 0, stream>>>(feat, fc_w, fc_b, x0);

  gn_stats_kernel<<<(512 * 512) / 4, 256, 0, stream>>>(x0, gw0, gb0, sc, sh, 512, 16);
  deconv_kernel<512, 4, 32, 64, 512><<<dim3(8, 512), 256, 0, stream>>>(x0, sc, sh, dw0, db0, x1, 256);

  gn_stats_kernel<<<(512 * 256) / 4, 256, 0, stream>>>(x1, gw1, gb1, sc, sh, 256, 64);
  deconv_kernel<256, 8, 16, 256, 128><<<dim3(8, 512), 256, 0, stream>>>(x1, sc, sh, dw1, db1, x2, 128);

  gn_stats_kernel<<<(512 * 128) / 4, 256, 0, stream>>>(x2, gw2, gb2, sc, sh, 128, 256);
  deconv_kernel<128, 16, 8, 256, 32><<<dim3(8, 512), 256, 0, stream>>>(x2, sc, sh, dw2, db2, x3, 64);

  gn_stats_kernel<<<(512 * 64) / 4, 256, 0, stream>>>(x3, nullptr, nullptr, sc, sh, 64, 1024);
  head_kernel<<<512, 256, 0, stream>>>(x3, sc, sh, action, hgw, hcw, (float*)d_out);
}

// Round 3
// 1975.415 us; speedup vs baseline: 4.4684x; 4.4684x over previous
//
#include <hip/hip_runtime.h>
#include <hip/hip_bf16.h>

#define DI __device__ __forceinline__

// pick component i (constant under full unroll) from a float4
#define F4C(v, i) ((i) == 0 ? (v).x : (i) == 1 ? (v).y : (i) == 2 ? (v).z : (v).w)

// ---------------- workspace layout (in floats) ----------------
// Region B: x0 (4.19M floats) then reused for x2 (16.78M)
// Region A: x1 (8.39M) then reused for x3 (33.55M)
static constexpr size_t OFF_REGB = 0;
static constexpr size_t OFF_REGA = 16777216;           // 64 MB in
static constexpr size_t OFF_SC   = 50331648;           // 192 MB in
static constexpr size_t OFF_SH   = OFF_SC + 262144;

// ---------------- fc1: x0[b,d,hw] = relu(sum_c feat[b,c,hw] * W[c,d] + b[d]) ----------------
__global__ __launch_bounds__(256)
void fc_kernel(const float* __restrict__ feat, const float* __restrict__ fw,
               const float* __restrict__ fb, float* __restrict__ x0)
{
  constexpr int CI = 256, CO = 512, S2 = 16;
  __shared__ __align__(16) float xs[CI * S2];
  const int b = blockIdx.x, t = threadIdx.x;
  const float4* fg = (const float4*)(feat + (size_t)b * CI * S2);
#pragma unroll
  for (int j = 0; j < 4; ++j)
    ((float4*)xs)[t + j * 256] = fg[t + j * 256];
  __syncthreads();
  const int hw = t & 15;
  const int d0 = (t >> 4) * 32;
  float acc[32];
#pragma unroll
  for (int j = 0; j < 32; ++j) acc[j] = 0.f;
  for (int c = 0; c < CI; ++c) {
    float xv = xs[c * S2 + hw];
    const float4* wr = (const float4*)(fw + c * CO + d0);
#pragma unroll
    for (int q = 0; q < 8; ++q) {
      float4 w4 = wr[q];
      acc[q * 4 + 0] += xv * w4.x;
      acc[q * 4 + 1] += xv * w4.y;
      acc[q * 4 + 2] += xv * w4.z;
      acc[q * 4 + 3] += xv * w4.w;
    }
  }
#pragma unroll
  for (int j = 0; j < 32; ++j) {
    int d = d0 + j;
    x0[((size_t)b * CO + d) * S2 + hw] = fmaxf(acc[j] + fb[d], 0.f);
  }
}

// ---------------- per-(b,c) norm stats -> scale/shift ----------------
__global__ void gn_stats_kernel(const float* __restrict__ x, const float* __restrict__ g,
                                const float* __restrict__ be, float* __restrict__ sc,
                                float* __restrict__ sh, int C, int S2)
{
  int wid = (blockIdx.x * 256 + threadIdx.x) >> 6;
  int lane = threadIdx.x & 63;
  const float* xp = x + (size_t)wid * S2;
  float s = 0.f, s2 = 0.f;
  for (int j = lane; j < S2; j += 64) { float v = xp[j]; s += v; s2 += v * v; }
#pragma unroll
  for (int off = 32; off; off >>= 1) { s += __shfl_xor(s, off, 64); s2 += __shfl_xor(s2, off, 64); }
  if (lane == 0) {
    float inv = 1.f / (float)S2;
    float mu = s * inv;
    float var = fmaxf(s2 * inv - mu * mu, 0.f);
    float rstd = rsqrtf(var + 1e-5f);
    int c = wid % C;
    float gamma = g ? g[c] : 1.f;
    float beta  = be ? be[c] : 0.f;
    float scale = gamma * rstd;
    sc[wid] = scale;
    sh[wid] = beta - mu * scale;
  }
}

// ---------------- deconv as quad-GEMM ----------------
// ConvTranspose2d(CI,CO,3,s=2,p=1,op=1): output quad (2iy..2iy+1, 2ix..2ix+1)
// consumes exactly the 9 taps against x[iy..iy+1][ix..ix+1] (zero-padded halo):
//   y[2iy  ,2ix  ] += w[1][1]*x00
//   y[2iy  ,2ix+1] += w[1][0]*x00 + w[1][2]*x01
//   y[2iy+1,2ix  ] += w[0][1]*x00 + w[2][1]*x10
//   y[2iy+1,2ix+1] += w[0][0]*x00 + w[0][2]*x01 + w[2][0]*x10 + w[2][2]*x11
// Block: 256 thr = 16(M) x 16(N); thread: 4 output chans x 4 quads (144 FMA/k).
// LDS: W chunk [9][KB][64] (36.9 KB) + zero-padded X chunk.
template<int STAGE>
__global__ __launch_bounds__(256, 3)
void deconv_gemm(const float* __restrict__ x, const float* __restrict__ sc,
                 const float* __restrict__ sh, const float* __restrict__ w,
                 const float* __restrict__ bias, float* __restrict__ y)
{
  constexpr int CI  = STAGE == 0 ? 512 : STAGE == 1 ? 256 : 128;
  constexpr int CO  = CI / 2;
  constexpr int H   = STAGE == 0 ? 4 : STAGE == 1 ? 8 : 16;
  constexpr int S2I = H * H, S2O = 4 * S2I;
  constexpr int KB  = 16;
  constexpr int NCH = CI / KB;
  constexpr int XST = STAGE == 0 ? 8 : STAGE == 1 ? 12 : 20;   // padded row stride
  constexpr int XSZ = STAGE == 0 ? KB * 4 * 5 * 8
                    : STAGE == 1 ? KB * 9 * 12
                                 : KB * 5 * 20;
  __shared__ __align__(16) float Xs[XSZ];
  __shared__ __align__(16) float Ws[9 * KB * 64];

  const int t  = threadIdx.x;
  const int mt = t & 15;          // M-thread: output channels mt*4..mt*4+3 (+m0)
  const int n  = t >> 4;          // N-thread: 4 quads

  int m0, b, iy, ix0, qz = 0, bl = 0;
  if constexpr (STAGE == 0)      { m0 = blockIdx.x * 64; bl = n >> 2; b = blockIdx.y * 4 + bl; iy = n & 3; ix0 = 0; }
  else if constexpr (STAGE == 1) { m0 = blockIdx.x * 64; b = blockIdx.y; iy = n >> 1; ix0 = (n & 1) * 4; }
  else                           { m0 = 0; qz = blockIdx.x; b = blockIdx.y; iy = n >> 2; ix0 = (n & 3) * 4; }

  // zero X once: pad slots are never written by data fills, stay zero
  for (int i = t; i < XSZ; i += 256) Xs[i] = 0.f;

  float acc[4][4][4];
#pragma unroll
  for (int mi = 0; mi < 4; ++mi)
#pragma unroll
    for (int q = 0; q < 4; ++q)
#pragma unroll
      for (int v = 0; v < 4; ++v) acc[mi][q][v] = 0.f;

  for (int ch = 0; ch < NCH; ++ch) {
    const int c0 = ch * KB;
    __syncthreads();   // prev compute done (first iter: zero-X done)

    // ---- stage W chunk: [9][KB][64] from w[m0+mo][c0..c0+KB)[9] ----
    {
      const float* wg = w + (size_t)m0 * CI * 9 + c0 * 9;
#pragma unroll
      for (int it = 0; it < 9; ++it) {
        int idx = t + it * 256;            // 64*36 = 2304 float4s
        int mo = idx / 36, j = idx - mo * 36;
        float4 v = ((const float4*)(wg + (size_t)mo * CI * 9))[j];
        int f = j * 4;
        { int fq = f;     int c = fq / 9, tp = fq - 9 * c; Ws[(tp * KB + c) * 64 + mo] = v.x; }
        { int fq = f + 1; int c = fq / 9, tp = fq - 9 * c; Ws[(tp * KB + c) * 64 + mo] = v.y; }
        { int fq = f + 2; int c = fq / 9, tp = fq - 9 * c; Ws[(tp * KB + c) * 64 + mo] = v.z; }
        { int fq = f + 3; int c = fq / 9, tp = fq - 9 * c; Ws[(tp * KB + c) * 64 + mo] = v.w; }
      }
    }

    // ---- stage X chunk (gn applied), zero-padded halo ----
    if constexpr (STAGE == 0) {
      int k = t >> 4, blf = (t >> 2) & 3, r = t & 3;
      int bb = blockIdx.y * 4 + blf;
      float scv = sc[(size_t)bb * CI + c0 + k], shv = sh[(size_t)bb * CI + c0 + k];
      float4 v = *(const float4*)(x + ((size_t)bb * CI + c0 + k) * 16 + r * 4);
      v.x = v.x * scv + shv; v.y = v.y * scv + shv; v.z = v.z * scv + shv; v.w = v.w * scv + shv;
      *(float4*)&Xs[((k * 4 + blf) * 5 + r) * 8] = v;
    } else if constexpr (STAGE == 1) {
      int k = t >> 4, r = (t >> 1) & 7, cg = t & 1;
      float scv = sc[(size_t)b * CI + c0 + k], shv = sh[(size_t)b * CI + c0 + k];
      float4 v = *(const float4*)(x + ((size_t)b * CI + c0 + k) * 64 + r * 8 + cg * 4);
      v.x = v.x * scv + shv; v.y = v.y * scv + shv; v.z = v.z * scv + shv; v.w = v.w * scv + shv;
      *(float4*)&Xs[(k * 9 + r) * 12 + cg * 4] = v;
    } else {
      if (qz < 3) {          // 5 rows incl. halo row (real data)
        for (int idx = t; idx < KB * 20; idx += 256) {
          int k = idx / 20, rem = idx - 20 * k, r = rem >> 2, cg = rem & 3;
          float scv = sc[(size_t)b * CI + c0 + k], shv = sh[(size_t)b * CI + c0 + k];
          float4 v = *(const float4*)(x + ((size_t)b * CI + c0 + k) * 256 + (qz * 4 + r) * 16 + cg * 4);
          v.x = v.x * scv + shv; v.y = v.y * scv + shv; v.z = v.z * scv + shv; v.w = v.w * scv + shv;
          *(float4*)&Xs[(k * 5 + r) * 20 + cg * 4] = v;
        }
      } else {               // last tile: halo row 16 is zero pad, load 4 rows
        for (int idx = t; idx < KB * 16; idx += 256) {
          int k = idx >> 4, rem = idx & 15, r = rem >> 2, cg = rem & 3;
          float scv = sc[(size_t)b * CI + c0 + k], shv = sh[(size_t)b * CI + c0 + k];
          float4 v = *(const float4*)(x + ((size_t)b * CI + c0 + k) * 256 + (12 + r) * 16 + cg * 4);
          v.x = v.x * scv + shv; v.y = v.y * scv + shv; v.z = v.z * scv + shv; v.w = v.w * scv + shv;
          *(float4*)&Xs[(k * 5 + r) * 20 + cg * 4] = v;
        }
      }
    }
    __syncthreads();

    // ---- compute ----
    const float4* Wp = (const float4*)Ws;
#pragma unroll 4
    for (int k = 0; k < KB; ++k) {
      int base;
      if constexpr (STAGE == 0)      base = ((k * 4 + bl) * 5 + iy) * XST;
      else if constexpr (STAGE == 1) base = (k * 9 + iy) * XST + ix0;
      else                           base = (k * 5 + iy) * XST + ix0;

      float4 x0v = *(const float4*)&Xs[base];
      float  x0e = Xs[base + 4];
      float4 x1v = *(const float4*)&Xs[base + XST];
      float  x1e = Xs[base + XST + 4];
      float xr0[5] = {x0v.x, x0v.y, x0v.z, x0v.w, x0e};
      float xr1[5] = {x1v.x, x1v.y, x1v.z, x1v.w, x1e};

      float4 wv[9];
#pragma unroll
      for (int tap = 0; tap < 9; ++tap)
        wv[tap] = Wp[(tap * KB + k) * 16 + mt];

#pragma unroll
      for (int q = 0; q < 4; ++q) {
        float a0 = xr0[q], a1 = xr0[q + 1];
        float b0 = xr1[q], b1 = xr1[q + 1];
#pragma unroll
        for (int mi = 0; mi < 4; ++mi) {
          acc[mi][q][0] = fmaf(F4C(wv[4], mi), a0, acc[mi][q][0]);
          acc[mi][q][1] = fmaf(F4C(wv[3], mi), a0, fmaf(F4C(wv[5], mi), a1, acc[mi][q][1]));
          acc[mi][q][2] = fmaf(F4C(wv[1], mi), a0, fmaf(F4C(wv[7], mi), b0, acc[mi][q][2]));
          acc[mi][q][3] = fmaf(F4C(wv[0], mi), a0,
                          fmaf(F4C(wv[2], mi), a1,
                          fmaf(F4C(wv[6], mi), b0,
                          fmaf(F4C(wv[8], mi), b1, acc[mi][q][3]))));
        }
      }
    }
  }

  // ---- epilogue: bias + relu, contiguous float4 stores ----
  const int iyg = (STAGE == 2) ? qz * 4 + iy : iy;
#pragma unroll
  for (int mi = 0; mi < 4; ++mi) {
    int m = m0 + mt * 4 + mi;
    float bv = bias[m];
    float* yp = y + ((size_t)b * CO + m) * S2O + (2 * iyg) * (2 * H) + 2 * ix0;
    float4 r0a = {fmaxf(acc[mi][0][0] + bv, 0.f), fmaxf(acc[mi][0][1] + bv, 0.f),
                  fmaxf(acc[mi][1][0] + bv, 0.f), fmaxf(acc[mi][1][1] + bv, 0.f)};
    float4 r0b = {fmaxf(acc[mi][2][0] + bv, 0.f), fmaxf(acc[mi][2][1] + bv, 0.f),
                  fmaxf(acc[mi][3][0] + bv, 0.f), fmaxf(acc[mi][3][1] + bv, 0.f)};
    float4 r1a = {fmaxf(acc[mi][0][2] + bv, 0.f), fmaxf(acc[mi][0][3] + bv, 0.f),
                  fmaxf(acc[mi][1][2] + bv, 0.f), fmaxf(acc[mi][1][3] + bv, 0.f)};
    float4 r1b = {fmaxf(acc[mi][2][2] + bv, 0.f), fmaxf(acc[mi][2][3] + bv, 0.f),
                  fmaxf(acc[mi][3][2] + bv, 0.f), fmaxf(acc[mi][3][3] + bv, 0.f)};
    *(float4*)yp = r0a;
    *(float4*)(yp + 4) = r0b;
    *(float4*)(yp + 2 * H) = r1a;
    *(float4*)(yp + 2 * H + 4) = r1b;
  }
}

// ---------------- block reductions ----------------
DI float breduce_sum(float v, float* buf) {
#pragma unroll
  for (int off = 32; off; off >>= 1) v += __shfl_xor(v, off, 64);
  if ((threadIdx.x & 63) == 0) buf[threadIdx.x >> 6] = v;
  __syncthreads();
  float r = (buf[0] + buf[1]) + (buf[2] + buf[3]);
  __syncthreads();
  return r;
}
DI float breduce_max(float v, float* buf) {
#pragma unroll
  for (int off = 32; off; off >>= 1) v = fmaxf(v, __shfl_xor(v, off, 64));
  if ((threadIdx.x & 63) == 0) buf[threadIdx.x >> 6] = v;
  __syncthreads();
  float r = fmaxf(fmaxf(buf[0], buf[1]), fmaxf(buf[2], buf[3]));
  __syncthreads();
  return r;
}

// ---------------- head: norm -> per-action 1x1 conv -> spatial softmax -> coords ----------------
__global__ __launch_bounds__(256)
void head_kernel(const float* __restrict__ x3, const float* __restrict__ sc,
                 const float* __restrict__ sh, const int* __restrict__ action,
                 const float* __restrict__ hgw, const float* __restrict__ hcw,
                 float* __restrict__ out)
{
  constexpr int C = 64, S = 5, P = 1024;
  const int b = blockIdx.x, t = threadIdx.x;
  const int a = action[b];
  __shared__ float weff[S * C];
  __shared__ float rbuf[4];
  for (int j = t; j < S * C; j += 256) {
    int s = j >> 6, c = j & 63;
    weff[j] = hcw[(a * S + s) * C + c] * hgw[a * C + c];
  }
  __syncthreads();

  float L[S][4];
#pragma unroll
  for (int s = 0; s < S; ++s)
#pragma unroll
    for (int k = 0; k < 4; ++k) L[s][k] = 0.f;

  const float* xb = x3 + (size_t)b * C * P;
  for (int c = 0; c < C; ++c) {
    float scv = sc[b * C + c], shv = sh[b * C + c];
    float xv[4];
#pragma unroll
    for (int k = 0; k < 4; ++k) xv[k] = xb[c * P + t + k * 256] * scv + shv;
#pragma unroll
    for (int s = 0; s < S; ++s) {
      float wv = weff[s * C + c];
#pragma unroll
      for (int k = 0; k < 4; ++k) L[s][k] += xv[k] * wv;
    }
  }

#pragma unroll
  for (int s = 0; s < S; ++s) {
    float m = fmaxf(fmaxf(L[s][0], L[s][1]), fmaxf(L[s][2], L[s][3]));
    m = breduce_max(m, rbuf);
    float se = 0.f, sx = 0.f, sy = 0.f;
#pragma unroll
    for (int k = 0; k < 4; ++k) {
      int p = t + k * 256;
      float e = __expf(L[s][k] - m);
      se += e;
      sx += e * ((float)(p & 31) * (2.f / 31.f) - 1.f);
      sy += e * ((float)(p >> 5) * (2.f / 31.f) - 1.f);
    }
    se = breduce_sum(se, rbuf);
    sx = breduce_sum(sx, rbuf);
    sy = breduce_sum(sy, rbuf);
    if (t == 0) {
      out[(b * S + s) * 2 + 0] = sx / se;
      out[(b * S + s) * 2 + 1] = sy / se;
    }
  }
}

// ---------------- launcher ----------------
extern "C" void kernel_launch(void* const* d_in, const int* in_sizes, int n_in,
                              void* d_out, int out_size, void* d_ws, size_t ws_size,
                              hipStream_t stream)
{
  (void)in_sizes; (void)n_in; (void)out_size; (void)ws_size;
  const float* feat   = (const float*)d_in[0];
  const int*   action = (const int*)d_in[1];
  const float* fc_w = (const float*)d_in[3];
  const float* fc_b = (const float*)d_in[4];
  const float* gw0  = (const float*)d_in[5];
  const float* gb0  = (const float*)d_in[6];
  const float* dw0  = (const float*)d_in[7];
  const float* db0  = (const float*)d_in[8];
  const float* gw1  = (const float*)d_in[9];
  const float* gb1  = (const float*)d_in[10];
  const float* dw1  = (const float*)d_in[11];
  const float* db1  = (const float*)d_in[12];
  const float* gw2  = (const float*)d_in[13];
  const float* gb2  = (const float*)d_in[14];
  const float* dw2  = (const float*)d_in[15];
  const float* db2  = (const float*)d_in[16];
  const float* hgw  = (const float*)d_in[17];
  const float* hcw  = (const float*)d_in[19];

  float* ws = (float*)d_ws;
  float* x0 = ws + OFF_REGB;
  float* x2 = ws + OFF_REGB;
  float* x1 = ws + OFF_REGA;
  float* x3 = ws + OFF_REGA;
  float* sc = ws + OFF_SC;
  float* sh = ws + OFF_SH;

  fc_kernel<<<512, 256, 0, stream>>>(feat, fc_w, fc_b, x0);

  gn_stats_kernel<<<(512 * 512) / 4, 256, 0, stream>>>(x0, gw0, gb0, sc, sh, 512, 16);
  deconv_gemm<0><<<dim3(4, 128), 256, 0, stream>>>(x0, sc, sh, dw0, db0, x1);

  gn_stats_kernel<<<(512 * 256) / 4, 256, 0, stream>>>(x1, gw1, gb1, sc, sh, 256, 64);
  deconv_gemm<1><<<dim3(2, 512), 256, 0, stream>>>(x1, sc, sh, dw1, db1, x2);

  gn_stats_kernel<<<(512 * 128) / 4, 256, 0, stream>>>(x2, gw2, gb2, sc, sh, 128, 256);
  deconv_gemm<2><<<dim3(4, 512), 256, 0, stream>>>(x2, sc, sh, dw2, db2, x3);

  gn_stats_kernel<<<(512 * 64) / 4, 256, 0, stream>>>(x3, nullptr, nullptr, sc, sh, 64, 1024);
  head_kernel<<<512, 256, 0, stream>>>(x3, sc, sh, action, hgw, hcw, (float*)d_out);
}